// Round 2
// baseline (241.530 us; speedup 1.0000x reference)
//
#include <hip/hip_runtime.h>
#include <math.h>

#define D_MODEL 1024
#define SEQ 2048
#define NBATCH 4

using bf16x8 = __attribute__((ext_vector_type(8))) short;
using f32x4  = __attribute__((ext_vector_type(4))) float;

__device__ __forceinline__ unsigned short f2bf(float f) {
  union { float f; unsigned int u; } v; v.f = f;
  return (unsigned short)((v.u + 0x7fffu + ((v.u >> 16) & 1u)) >> 16);
}

__device__ __forceinline__ void async_cp16(const void* g, void* l) {
  __builtin_amdgcn_global_load_lds(
      (const __attribute__((address_space(1))) void*)g,
      (__attribute__((address_space(3))) void*)l, 16, 0, 0);
}

// Stage one 128x32 bf16 tile pair into seg-major LDS:
//   addr_elem(row, seg) = seg*1024 + row*8   (seg = k-chunk of 8 elems, 0..3)
// Thread mapping (lane=tid&63, w=tid>>6): instr0 covers (row=(w&1)*64+lane,
// seg=w>>1) at LDS elem tid*8; instr1 is seg+2 at +2048 elems. The global
// pointers gA/gB must already point at (row, seg) for k0=0.
__device__ __forceinline__ void stage_tile(const unsigned short* gA,
                                           const unsigned short* gB,
                                           unsigned short* As,
                                           unsigned short* Bs, int tid) {
  async_cp16(gA,      As + tid * 8);
  async_cp16(gA + 16, As + tid * 8 + 2048);
  async_cp16(gB,      Bs + tid * 8);
  async_cp16(gB + 16, Bs + tid * 8 + 2048);
}

// ---------- prep_x: x fp32 -> bf16; s = x@Wo + bo; t = tanh(s) ----------
__global__ __launch_bounds__(256) void prep_x_kernel(
    const float* __restrict__ x, const float* __restrict__ Wo,
    const float* __restrict__ bo, unsigned short* __restrict__ xb,
    float* __restrict__ tb) {
  const int m = blockIdx.x;
  const int tid = threadIdx.x;
  const float4 xv = ((const float4*)(x + (size_t)m * D_MODEL))[tid];
  const float4 wv = ((const float4*)Wo)[tid];
  ushort4 o;
  o.x = f2bf(xv.x); o.y = f2bf(xv.y); o.z = f2bf(xv.z); o.w = f2bf(xv.w);
  ((ushort4*)(xb + (size_t)m * D_MODEL))[tid] = o;
  float p = xv.x * wv.x + xv.y * wv.y + xv.z * wv.z + xv.w * wv.w;
  #pragma unroll
  for (int off = 32; off > 0; off >>= 1) p += __shfl_down(p, off, 64);
  __shared__ float red[4];
  if ((tid & 63) == 0) red[tid >> 6] = p;
  __syncthreads();
  if (tid == 0) {
    float s = red[0] + red[1] + red[2] + red[3] + bo[0];
    tb[m] = tanhf(s);
  }
}

// ---------- prep_w: transpose W (K x N) -> WT (N x K) in bf16 ----------
__global__ __launch_bounds__(256) void prep_w_kernel(
    const float* __restrict__ Wq, const float* __restrict__ Wk,
    unsigned short* __restrict__ WqT, unsigned short* __restrict__ WkT) {
  const float* W = blockIdx.z ? Wk : Wq;
  unsigned short* WT = blockIdx.z ? WkT : WqT;
  const int k0 = blockIdx.y * 32, n0 = blockIdx.x * 32;
  __shared__ unsigned short lds[32][36];
  const int tid = threadIdx.x;
  const int r = tid >> 3, c = (tid & 7) * 4;
  float4 v = *(const float4*)(&W[(size_t)(k0 + r) * D_MODEL + n0 + c]);
  lds[r][c + 0] = f2bf(v.x); lds[r][c + 1] = f2bf(v.y);
  lds[r][c + 2] = f2bf(v.z); lds[r][c + 3] = f2bf(v.w);
  __syncthreads();
  ushort4 o;
  o.x = lds[c + 0][r]; o.y = lds[c + 1][r];
  o.z = lds[c + 2][r]; o.w = lds[c + 3][r];
  *(ushort4*)(&WT[(size_t)(n0 + r) * D_MODEL + k0 + c]) = o;
}

// ---------- qkgen: C = xb @ Bt^T + bias, bf16 out ----------
// 128x128 tile, BK=32, 4 waves x (64x64), seg-major LDS, dbuf issue-ahead.
__global__ __launch_bounds__(256, 3) void qkgen_kernel(
    const unsigned short* __restrict__ xb,
    const unsigned short* __restrict__ WqT,
    const unsigned short* __restrict__ WkT,
    const float* __restrict__ bq, const float* __restrict__ bk,
    unsigned short* __restrict__ Qb, unsigned short* __restrict__ Kb) {
  const unsigned short* Bt = blockIdx.z ? WkT : WqT;
  const float* bias = blockIdx.z ? bk : bq;
  unsigned short* Cout = blockIdx.z ? Kb : Qb;
  const int m0 = blockIdx.x * 128;
  const int n0 = blockIdx.y * 128;
  __shared__ unsigned short As[2][4096];
  __shared__ unsigned short Bs[2][4096];
  const int tid = threadIdx.x;
  const int lane = tid & 63, w = tid >> 6;
  const int wm = w >> 1, wn = w & 1;
  const int l16 = lane & 15, quad = lane >> 4;

  f32x4 acc[4][4];
  #pragma unroll
  for (int i = 0; i < 4; i++)
    #pragma unroll
    for (int j = 0; j < 4; j++) acc[i][j] = f32x4{0.f, 0.f, 0.f, 0.f};

  const int strow = (w & 1) * 64 + lane;
  const int stseg = (w >> 1) * 8;
  const unsigned short* gA = xb + (size_t)(m0 + strow) * D_MODEL + stseg;
  const unsigned short* gB = Bt + (size_t)(n0 + strow) * D_MODEL + stseg;

  stage_tile(gA, gB, As[0], Bs[0], tid);
  __syncthreads();

  #pragma unroll 2
  for (int kk = 0; kk < 32; ++kk) {
    const int cur = kk & 1;
    if (kk < 31)
      stage_tile(gA + (kk + 1) * 32, gB + (kk + 1) * 32,
                 As[cur ^ 1], Bs[cur ^ 1], tid);
    bf16x8 af[4], bfr[4];
    #pragma unroll
    for (int mt = 0; mt < 4; mt++)
      af[mt] = *(const bf16x8*)(&As[cur][quad * 1024 + (wm * 64 + mt * 16 + l16) * 8]);
    #pragma unroll
    for (int nt = 0; nt < 4; nt++)
      bfr[nt] = *(const bf16x8*)(&Bs[cur][quad * 1024 + (wn * 64 + nt * 16 + l16) * 8]);
    #pragma unroll
    for (int mt = 0; mt < 4; mt++)
      #pragma unroll
      for (int nt = 0; nt < 4; nt++)
        acc[mt][nt] = __builtin_amdgcn_mfma_f32_16x16x32_bf16(
            af[mt], bfr[nt], acc[mt][nt], 0, 0, 0);
    __syncthreads();
  }

  float bv[4];
  #pragma unroll
  for (int nt = 0; nt < 4; nt++) bv[nt] = bias[n0 + wn * 64 + nt * 16 + l16];
  #pragma unroll
  for (int mt = 0; mt < 4; mt++) {
    #pragma unroll
    for (int r = 0; r < 4; r++) {
      const int row = m0 + wm * 64 + mt * 16 + quad * 4 + r;
      unsigned short* cp = Cout + (size_t)row * D_MODEL + n0 + wn * 64 + l16;
      #pragma unroll
      for (int nt = 0; nt < 4; nt++)
        cp[nt * 16] = f2bf(acc[mt][nt][r] + bv[nt]);
    }
  }
}

// ---------- qkt: out[b,i,j] = 2^-5 * Q_i . K_j + 5*tanh(s_j - s_i) ----------
__global__ __launch_bounds__(256, 3) void qkt_kernel(
    const unsigned short* __restrict__ Qb,
    const unsigned short* __restrict__ Kb,
    const float* __restrict__ tb, float* __restrict__ out) {
  const int b = blockIdx.z;
  const int i0 = blockIdx.x * 128;
  const int j0 = blockIdx.y * 128;
  const unsigned short* A = Qb + (size_t)b * SEQ * D_MODEL;
  const unsigned short* Bt = Kb + (size_t)b * SEQ * D_MODEL;
  __shared__ unsigned short As[2][4096];
  __shared__ unsigned short Bs[2][4096];
  __shared__ float tsi[128], tsj[128];
  const int tid = threadIdx.x;
  if (tid < 128) tsi[tid] = tb[b * SEQ + i0 + tid];
  else           tsj[tid - 128] = tb[b * SEQ + j0 + tid - 128];
  const int lane = tid & 63, w = tid >> 6;
  const int wm = w >> 1, wn = w & 1;
  const int l16 = lane & 15, quad = lane >> 4;

  f32x4 acc[4][4];
  #pragma unroll
  for (int i = 0; i < 4; i++)
    #pragma unroll
    for (int j = 0; j < 4; j++) acc[i][j] = f32x4{0.f, 0.f, 0.f, 0.f};

  const int strow = (w & 1) * 64 + lane;
  const int stseg = (w >> 1) * 8;
  const unsigned short* gA = A + (size_t)(i0 + strow) * D_MODEL + stseg;
  const unsigned short* gB = Bt + (size_t)(j0 + strow) * D_MODEL + stseg;

  stage_tile(gA, gB, As[0], Bs[0], tid);
  __syncthreads();

  #pragma unroll 2
  for (int kk = 0; kk < 32; ++kk) {
    const int cur = kk & 1;
    if (kk < 31)
      stage_tile(gA + (kk + 1) * 32, gB + (kk + 1) * 32,
                 As[cur ^ 1], Bs[cur ^ 1], tid);
    bf16x8 af[4], bfr[4];
    #pragma unroll
    for (int mt = 0; mt < 4; mt++)
      af[mt] = *(const bf16x8*)(&As[cur][quad * 1024 + (wm * 64 + mt * 16 + l16) * 8]);
    #pragma unroll
    for (int nt = 0; nt < 4; nt++)
      bfr[nt] = *(const bf16x8*)(&Bs[cur][quad * 1024 + (wn * 64 + nt * 16 + l16) * 8]);
    #pragma unroll
    for (int mt = 0; mt < 4; mt++)
      #pragma unroll
      for (int nt = 0; nt < 4; nt++)
        acc[mt][nt] = __builtin_amdgcn_mfma_f32_16x16x32_bf16(
            af[mt], bfr[nt], acc[mt][nt], 0, 0, 0);
    __syncthreads();
  }

  float tj[4];
  #pragma unroll
  for (int nt = 0; nt < 4; nt++) tj[nt] = tsj[wn * 64 + nt * 16 + l16];
  #pragma unroll
  for (int mt = 0; mt < 4; mt++) {
    #pragma unroll
    for (int r = 0; r < 4; r++) {
      const int il = wm * 64 + mt * 16 + quad * 4 + r;
      const float ti = tsi[il];
      float* cp = out + ((size_t)(b * SEQ + i0 + il)) * SEQ + j0 + wn * 64 + l16;
      #pragma unroll
      for (int nt = 0; nt < 4; nt++) {
        // tanh(sj - si) = (tj - ti) / (1 - tj*ti)
        const float num = tj[nt] - ti;
        const float den = fmaf(-tj[nt], ti, 1.0f);
        const float obias = 5.0f * num * __builtin_amdgcn_rcpf(den);
        cp[nt * 16] = 0.03125f * acc[mt][nt][r] + obias;
      }
    }
  }
}

extern "C" void kernel_launch(void* const* d_in, const int* in_sizes, int n_in,
                              void* d_out, int out_size, void* d_ws, size_t ws_size,
                              hipStream_t stream) {
  const float* x  = (const float*)d_in[0];
  const float* Wq = (const float*)d_in[1];
  const float* bq = (const float*)d_in[2];
  const float* Wk = (const float*)d_in[3];
  const float* bk = (const float*)d_in[4];
  const float* Wo = (const float*)d_in[5];
  const float* bo = (const float*)d_in[6];
  float* out = (float*)d_out;

  char* ws = (char*)d_ws;
  unsigned short* xb  = (unsigned short*)(ws);                        // 16 MiB
  unsigned short* WqT = (unsigned short*)(ws + (16ull << 20));        // 2 MiB
  unsigned short* WkT = (unsigned short*)(ws + (18ull << 20));        // 2 MiB
  unsigned short* Qb  = (unsigned short*)(ws + (20ull << 20));        // 16 MiB
  unsigned short* Kb  = (unsigned short*)(ws + (36ull << 20));        // 16 MiB
  float*          tb  = (float*)(ws + (52ull << 20));                 // 32 KiB

  prep_x_kernel<<<8192, 256, 0, stream>>>(x, Wo, bo, xb, tb);
  prep_w_kernel<<<dim3(32, 32, 2), 256, 0, stream>>>(Wq, Wk, WqT, WkT);
  qkgen_kernel<<<dim3(64, 8, 2), 256, 0, stream>>>(xb, WqT, WkT, bq, bk, Qb, Kb);
  qkt_kernel<<<dim3(16, 16, 4), 256, 0, stream>>>(Qb, Kb, tb, out);
}

// Round 3
// 195.233 us; speedup vs baseline: 1.2371x; 1.2371x over previous
//
#include <hip/hip_runtime.h>
#include <math.h>

#define D_MODEL 1024
#define SEQ 2048
#define SCALE 0.03125f

using bf16x8 = __attribute__((ext_vector_type(8))) short;
using f32x4  = __attribute__((ext_vector_type(4))) float;

__device__ __forceinline__ unsigned short f2bf(float f) {
  union { float f; unsigned int u; } v; v.f = f;
  return (unsigned short)((v.u + 0x7fffu + ((v.u >> 16) & 1u)) >> 16);
}

__device__ __forceinline__ void async_cp16(const void* g, void* l) {
  __builtin_amdgcn_global_load_lds(
      (const __attribute__((address_space(1))) void*)g,
      (__attribute__((address_space(3))) void*)l, 16, 0, 0);
}

// Per-thread global staging pointer for the swizzled 128x32 tile.
// Thread tid stages row r0=tid>>2, seg s0=(tid&3)^((r0>>1)&3) into LDS chunk
// index tid (and row r0+64 into chunk 256+tid). LDS chunk c holds
// (row=c>>2, seg=(c&3)^((row>>1)&3)) -> fragment b128 reads are 2-way
// bank-aliased (free), staging keeps R1's 64B-span coalescing.
__device__ __forceinline__ const unsigned short* stage_ptr(
    const unsigned short* base, int row0, int ld, int tid) {
  const int r0 = tid >> 2;
  const int s0 = ((tid & 3) ^ ((r0 >> 1) & 3)) * 8;
  return base + (size_t)(row0 + r0) * ld + s0;
}

// C[128x128] += A(rows m0..m0+127) x B^T(rows n0..n0+127), K=1024, BK=32,
// double-buffered swizzled LDS, issue-ahead staging, one barrier per iter.
__device__ __forceinline__ void gemm_core(
    const unsigned short* __restrict__ gA, const unsigned short* __restrict__ gB,
    int lda, int ldb, unsigned short* As, unsigned short* Bs, int tid,
    f32x4 acc[4][4]) {
  const int lane = tid & 63, w = tid >> 6;
  const int wm = w >> 1, wn = w & 1;
  const int l16 = lane & 15, quad = lane >> 4;

  async_cp16(gA,            As + tid * 8);
  async_cp16(gA + 64 * lda, As + 2048 + tid * 8);
  async_cp16(gB,            Bs + tid * 8);
  async_cp16(gB + 64 * ldb, Bs + 2048 + tid * 8);
  __syncthreads();

  #pragma unroll 2
  for (int kk = 0; kk < 32; ++kk) {
    const int cur = (kk & 1) * 4096;
    const int nxt = 4096 - cur;
    if (kk < 31) {
      const unsigned short* a = gA + (kk + 1) * 32;
      const unsigned short* b = gB + (kk + 1) * 32;
      async_cp16(a,            As + nxt + tid * 8);
      async_cp16(a + 64 * lda, As + nxt + 2048 + tid * 8);
      async_cp16(b,            Bs + nxt + tid * 8);
      async_cp16(b + 64 * ldb, Bs + nxt + 2048 + tid * 8);
    }
    bf16x8 afr[4], bfr[4];
    #pragma unroll
    for (int mt = 0; mt < 4; mt++) {
      const int R = wm * 64 + mt * 16 + l16;
      afr[mt] = *(const bf16x8*)(As + cur + (R * 4 + (quad ^ ((R >> 1) & 3))) * 8);
    }
    #pragma unroll
    for (int nt = 0; nt < 4; nt++) {
      const int R = wn * 64 + nt * 16 + l16;
      bfr[nt] = *(const bf16x8*)(Bs + cur + (R * 4 + (quad ^ ((R >> 1) & 3))) * 8);
    }
    #pragma unroll
    for (int mt = 0; mt < 4; mt++)
      #pragma unroll
      for (int nt = 0; nt < 4; nt++)
        acc[mt][nt] = __builtin_amdgcn_mfma_f32_16x16x32_bf16(
            afr[mt], bfr[nt], acc[mt][nt], 0, 0, 0);
    __syncthreads();
  }
}

__device__ __forceinline__ void store_c_bf16(f32x4 acc[4][4],
                                             unsigned short* C, int ldc,
                                             int m0, int n0, int tid) {
  const int lane = tid & 63, w = tid >> 6;
  const int wm = w >> 1, wn = w & 1;
  const int l16 = lane & 15, quad = lane >> 4;
  #pragma unroll
  for (int mt = 0; mt < 4; mt++) {
    #pragma unroll
    for (int r = 0; r < 4; r++) {
      const int row = m0 + wm * 64 + mt * 16 + quad * 4 + r;
      unsigned short* cp = C + (size_t)row * ldc + n0 + wn * 64 + l16;
      #pragma unroll
      for (int nt = 0; nt < 4; nt++) cp[nt * 16] = f2bf(acc[mt][nt][r]);
    }
  }
}

// ---- wcvt: W fp32 -> bf16 rows; u = Wq bk, v = Wk bq, sc = scale*(bq.bk) ----
__global__ __launch_bounds__(256) void wcvt_kernel(
    const float* __restrict__ Wq, const float* __restrict__ Wk,
    const float* __restrict__ bq, const float* __restrict__ bk,
    unsigned short* __restrict__ Wqb, unsigned short* __restrict__ Wkb,
    float* __restrict__ u, float* __restrict__ v, float* __restrict__ sc) {
  const int blk = blockIdx.x, tid = threadIdx.x;
  __shared__ float red[4];
  float p;
  if (blk < 2048) {
    const bool isq = blk < 1024;
    const int row = blk & 1023;
    const float* W = isq ? Wq : Wk;
    const float* bias = isq ? bk : bq;
    const float4 wv = ((const float4*)(W + (size_t)row * D_MODEL))[tid];
    const float4 bv = ((const float4*)bias)[tid];
    ushort4 o;
    o.x = f2bf(wv.x); o.y = f2bf(wv.y); o.z = f2bf(wv.z); o.w = f2bf(wv.w);
    ((ushort4*)((isq ? Wqb : Wkb) + (size_t)row * D_MODEL))[tid] = o;
    p = wv.x * bv.x + wv.y * bv.y + wv.z * bv.z + wv.w * bv.w;
    #pragma unroll
    for (int off = 32; off > 0; off >>= 1) p += __shfl_down(p, off, 64);
    if ((tid & 63) == 0) red[tid >> 6] = p;
    __syncthreads();
    if (tid == 0) (isq ? u : v)[row] = red[0] + red[1] + red[2] + red[3];
  } else {
    const float4 a = ((const float4*)bq)[tid];
    const float4 b = ((const float4*)bk)[tid];
    p = a.x * b.x + a.y * b.y + a.z * b.z + a.w * b.w;
    #pragma unroll
    for (int off = 32; off > 0; off >>= 1) p += __shfl_down(p, off, 64);
    if ((tid & 63) == 0) red[tid >> 6] = p;
    __syncthreads();
    if (tid == 0) sc[0] = SCALE * (red[0] + red[1] + red[2] + red[3]);
  }
}

// ---- prep_x: xb=bf16(x); t=tanh(x.Wo+bo); aa=scale*(x.u)+sc; bb=scale*(x.v) ----
__global__ __launch_bounds__(256) void prep_x_kernel(
    const float* __restrict__ x, const float* __restrict__ Wo,
    const float* __restrict__ bo, const float* __restrict__ u,
    const float* __restrict__ v, const float* __restrict__ sc,
    unsigned short* __restrict__ xb, float* __restrict__ tb,
    float* __restrict__ aa, float* __restrict__ bb) {
  const int m = blockIdx.x, tid = threadIdx.x;
  const float4 xv = ((const float4*)(x + (size_t)m * D_MODEL))[tid];
  const float4 wv = ((const float4*)Wo)[tid];
  const float4 uv = ((const float4*)u)[tid];
  const float4 vv = ((const float4*)v)[tid];
  ushort4 o;
  o.x = f2bf(xv.x); o.y = f2bf(xv.y); o.z = f2bf(xv.z); o.w = f2bf(xv.w);
  ((ushort4*)(xb + (size_t)m * D_MODEL))[tid] = o;
  float p0 = xv.x * wv.x + xv.y * wv.y + xv.z * wv.z + xv.w * wv.w;
  float p1 = xv.x * uv.x + xv.y * uv.y + xv.z * uv.z + xv.w * uv.w;
  float p2 = xv.x * vv.x + xv.y * vv.y + xv.z * vv.z + xv.w * vv.w;
  #pragma unroll
  for (int off = 32; off > 0; off >>= 1) {
    p0 += __shfl_down(p0, off, 64);
    p1 += __shfl_down(p1, off, 64);
    p2 += __shfl_down(p2, off, 64);
  }
  __shared__ float red[3][4];
  if ((tid & 63) == 0) {
    red[0][tid >> 6] = p0; red[1][tid >> 6] = p1; red[2][tid >> 6] = p2;
  }
  __syncthreads();
  if (tid == 0) {
    tb[m] = tanhf(red[0][0] + red[0][1] + red[0][2] + red[0][3] + bo[0]);
    aa[m] = SCALE * (red[1][0] + red[1][1] + red[1][2] + red[1][3]) + sc[0];
    bb[m] = SCALE * (red[2][0] + red[2][1] + red[2][2] + red[2][3]);
  }
}

// ---- wmm: Mt[d2,d1] = sum_e Wk[d2,e]*Wq[d1,e]  (A=Wkb, B^T=Wqb) ----
__global__ __launch_bounds__(256, 3) void wmm_kernel(
    const unsigned short* __restrict__ Wkb,
    const unsigned short* __restrict__ Wqb, unsigned short* __restrict__ Mt) {
  const int m0 = blockIdx.x * 128, n0 = blockIdx.y * 128;
  __shared__ unsigned short As[2 * 4096], Bs[2 * 4096];
  const int tid = threadIdx.x;
  f32x4 acc[4][4];
  #pragma unroll
  for (int i = 0; i < 4; i++)
    #pragma unroll
    for (int j = 0; j < 4; j++) acc[i][j] = f32x4{0.f, 0.f, 0.f, 0.f};
  gemm_core(stage_ptr(Wkb, m0, D_MODEL, tid), stage_ptr(Wqb, n0, D_MODEL, tid),
            D_MODEL, D_MODEL, As, Bs, tid, acc);
  store_c_bf16(acc, Mt, D_MODEL, m0, n0, tid);
}

// ---- zgen: Zb = xb @ M  (B^T = Mt rows) ----
__global__ __launch_bounds__(256, 3) void zgen_kernel(
    const unsigned short* __restrict__ xb,
    const unsigned short* __restrict__ Mt, unsigned short* __restrict__ Zb) {
  const int m0 = blockIdx.x * 128, n0 = blockIdx.y * 128;
  __shared__ unsigned short As[2 * 4096], Bs[2 * 4096];
  const int tid = threadIdx.x;
  f32x4 acc[4][4];
  #pragma unroll
  for (int i = 0; i < 4; i++)
    #pragma unroll
    for (int j = 0; j < 4; j++) acc[i][j] = f32x4{0.f, 0.f, 0.f, 0.f};
  gemm_core(stage_ptr(xb, m0, D_MODEL, tid), stage_ptr(Mt, n0, D_MODEL, tid),
            D_MODEL, D_MODEL, As, Bs, tid, acc);
  store_c_bf16(acc, Zb, D_MODEL, m0, n0, tid);
}

// ---- zxt: out[b,i,j] = scale*(Z_i . x_j) + aa_i + bb_j + 5*tanh(s_j-s_i) ----
__global__ __launch_bounds__(256, 3) void zxt_kernel(
    const unsigned short* __restrict__ Zb, const unsigned short* __restrict__ xb,
    const float* __restrict__ tb, const float* __restrict__ aa,
    const float* __restrict__ bb, float* __restrict__ out) {
  const int b = blockIdx.z;
  const int i0 = blockIdx.x * 128, j0 = blockIdx.y * 128;
  __shared__ unsigned short As[2 * 4096], Bs[2 * 4096];
  __shared__ float tsi[128], tsj[128], tsa[128], tsb[128];
  const int tid = threadIdx.x;
  if (tid < 128) {
    tsi[tid] = tb[b * SEQ + i0 + tid];
    tsa[tid] = aa[b * SEQ + i0 + tid];
  } else {
    tsj[tid - 128] = tb[b * SEQ + j0 + tid - 128];
    tsb[tid - 128] = bb[b * SEQ + j0 + tid - 128];
  }
  f32x4 acc[4][4];
  #pragma unroll
  for (int i = 0; i < 4; i++)
    #pragma unroll
    for (int j = 0; j < 4; j++) acc[i][j] = f32x4{0.f, 0.f, 0.f, 0.f};
  const unsigned short* A = Zb + (size_t)b * SEQ * D_MODEL;
  const unsigned short* Bt = xb + (size_t)b * SEQ * D_MODEL;
  gemm_core(stage_ptr(A, i0, D_MODEL, tid), stage_ptr(Bt, j0, D_MODEL, tid),
            D_MODEL, D_MODEL, As, Bs, tid, acc);

  const int lane = tid & 63, w = tid >> 6;
  const int wm = w >> 1, wn = w & 1;
  const int l16 = lane & 15, quad = lane >> 4;
  float tj[4], bj[4];
  #pragma unroll
  for (int nt = 0; nt < 4; nt++) {
    tj[nt] = tsj[wn * 64 + nt * 16 + l16];
    bj[nt] = tsb[wn * 64 + nt * 16 + l16];
  }
  #pragma unroll
  for (int mt = 0; mt < 4; mt++) {
    #pragma unroll
    for (int r = 0; r < 4; r++) {
      const int il = wm * 64 + mt * 16 + quad * 4 + r;
      const float ti = tsi[il];
      const float ai = tsa[il];
      float* cp = out + ((size_t)(b * SEQ + i0 + il)) * SEQ + j0 + wn * 64 + l16;
      #pragma unroll
      for (int nt = 0; nt < 4; nt++) {
        const float num = tj[nt] - ti;
        const float den = fmaf(-tj[nt], ti, 1.0f);
        const float obias = 5.0f * num * __builtin_amdgcn_rcpf(den);
        cp[nt * 16] = SCALE * acc[mt][nt][r] + ai + bj[nt] + obias;
      }
    }
  }
}

extern "C" void kernel_launch(void* const* d_in, const int* in_sizes, int n_in,
                              void* d_out, int out_size, void* d_ws, size_t ws_size,
                              hipStream_t stream) {
  const float* x  = (const float*)d_in[0];
  const float* Wq = (const float*)d_in[1];
  const float* bq = (const float*)d_in[2];
  const float* Wk = (const float*)d_in[3];
  const float* bk = (const float*)d_in[4];
  const float* Wo = (const float*)d_in[5];
  const float* bo = (const float*)d_in[6];
  float* out = (float*)d_out;

  char* ws = (char*)d_ws;
  unsigned short* xb  = (unsigned short*)(ws);                      // 16 MiB
  unsigned short* Zb  = (unsigned short*)(ws + (16ull << 20));      // 16 MiB
  unsigned short* Wqb = (unsigned short*)(ws + (32ull << 20));      // 2 MiB
  unsigned short* Wkb = (unsigned short*)(ws + (34ull << 20));      // 2 MiB
  unsigned short* Mt  = (unsigned short*)(ws + (36ull << 20));      // 2 MiB
  float* tb = (float*)(ws + (38ull << 20));                         // 32 KiB
  float* aa = (float*)(ws + (38ull << 20) + (32ull << 10));         // 32 KiB
  float* bb = (float*)(ws + (38ull << 20) + (64ull << 10));         // 32 KiB
  float* u  = (float*)(ws + (38ull << 20) + (96ull << 10));         // 4 KiB
  float* v  = (float*)(ws + (38ull << 20) + (100ull << 10));        // 4 KiB
  float* sc = (float*)(ws + (38ull << 20) + (104ull << 10));        // 4 B

  wcvt_kernel<<<2049, 256, 0, stream>>>(Wq, Wk, bq, bk, Wqb, Wkb, u, v, sc);
  prep_x_kernel<<<8192, 256, 0, stream>>>(x, Wo, bo, u, v, sc, xb, tb, aa, bb);
  wmm_kernel<<<dim3(8, 8), 256, 0, stream>>>(Wkb, Wqb, Mt);
  zgen_kernel<<<dim3(64, 8), 256, 0, stream>>>(xb, Mt, Zb);
  zxt_kernel<<<dim3(16, 16, 4), 256, 0, stream>>>(Zb, xb, tb, aa, bb, out);
}